// Round 5
// baseline (413.437 us; speedup 1.0000x reference)
//
#include <hip/hip_runtime.h>
#include <stdint.h>
#include <math.h>

using short8   = __attribute__((ext_vector_type(8))) short;
using ushort4v = __attribute__((ext_vector_type(4))) unsigned short;
using f32x4    = __attribute__((ext_vector_type(4))) float;

#define B_ 2
#define S_ 64
#define K_ 64
#define D_ 256
#define C_ 32
#define N_ 4096  /* S_*K_ */

__device__ __forceinline__ float b2f(unsigned short u) {
    unsigned int v = ((unsigned int)u) << 16;
    return __builtin_bit_cast(float, v);
}
__device__ __forceinline__ unsigned short f2b(float f) {   // RNE f32->bf16
    unsigned int x = __builtin_bit_cast(unsigned int, f);
    x += 0x7fffu + ((x >> 16) & 1u);
    return (unsigned short)(x >> 16);
}

// load 8 consecutive f32, produce hi/lo split-bf16 fragments (hi+lo ~ 2^-17 rel)
__device__ __forceinline__ void cvt8(const float* p, short8& hi, short8& lo) {
    f32x4 a = *(const f32x4*)p;
    f32x4 c = *(const f32x4*)(p + 4);
#pragma unroll
    for (int e = 0; e < 4; ++e) {
        unsigned short h0 = f2b(a[e]);
        hi[e]     = (short)h0; lo[e]     = (short)f2b(a[e] - b2f(h0));
        unsigned short h1 = f2b(c[e]);
        hi[e + 4] = (short)h1; lo[e + 4] = (short)f2b(c[e] - b2f(h1));
    }
}
__device__ __forceinline__ void cvt8h(const float* p, short8& hi) {
    f32x4 a = *(const f32x4*)p;
    f32x4 c = *(const f32x4*)(p + 4);
#pragma unroll
    for (int e = 0; e < 4; ++e) {
        hi[e]     = (short)f2b(a[e]);
        hi[e + 4] = (short)f2b(c[e]);
    }
}

// ---------------------------------------------------------------------------
// Kernel 1: QKV projections from f32 x, W. One wave = 16-token x 16-channel.
// ct 0-1 -> Q (hi/lo split), 2-3 -> K (hi/lo), 4-19 -> V (single bf16).
// Q,K stored [B][N][C] bf16 (hi and lo planes); V stored [B][D][N] bf16.
// ---------------------------------------------------------------------------
__global__ __launch_bounds__(256) void qkv_kernel(
    const float* __restrict__ x,
    const float* __restrict__ Wq, const float* __restrict__ bq,
    const float* __restrict__ Wk, const float* __restrict__ bk,
    const float* __restrict__ Wv, const float* __restrict__ bv,
    unsigned short* __restrict__ Qh, unsigned short* __restrict__ Ql,
    unsigned short* __restrict__ Kh, unsigned short* __restrict__ Kl,
    unsigned short* __restrict__ Vm)
{
    int widx = blockIdx.x * 4 + (threadIdx.x >> 6);   // 0..10239
    int lane = threadIdx.x & 63;
    int ttile = widx / 20;        // token tile of 16 (0..511)
    int ct    = widx % 20;        // channel tile
    int b  = ttile >> 8;
    int n0 = (ttile & 255) << 4;
    int col = lane & 15, g = lane >> 4;

    int n = n0 + col;
    int s = n & (S_ - 1), kk = n >> 6;
    const float* xrow = x + (((size_t)(b * S_ + s)) * K_ + kk) * D_;

    f32x4 acc = {0.f, 0.f, 0.f, 0.f};

    if (ct < 4) {                       // Q or K: hi/lo split path
        const float* W; const float* bias; int c0;
        if (ct < 2) { W = Wq; bias = bq; c0 = ct * 16; }
        else        { W = Wk; bias = bk; c0 = (ct - 2) * 16; }
        const float* wrow = W + (size_t)(c0 + col) * D_;
#pragma unroll
        for (int dc = 0; dc < 8; ++dc) {
            short8 xh, xl, wh, wl;
            cvt8(xrow + dc * 32 + g * 8, xh, xl);
            cvt8(wrow + dc * 32 + g * 8, wh, wl);
            acc = __builtin_amdgcn_mfma_f32_16x16x32_bf16(xl, wh, acc, 0, 0, 0);
            acc = __builtin_amdgcn_mfma_f32_16x16x32_bf16(xh, wl, acc, 0, 0, 0);
            acc = __builtin_amdgcn_mfma_f32_16x16x32_bf16(xh, wh, acc, 0, 0, 0);
        }
        float bb = bias[c0 + col];
        unsigned short* Th = (ct < 2) ? Qh : Kh;
        unsigned short* Tl = (ct < 2) ? Ql : Kl;
#pragma unroll
        for (int r = 0; r < 4; ++r) {
            int tok = n0 + g * 4 + r;
            float v = acc[r] + bb;
            unsigned short h = f2b(v);
            size_t idx = ((size_t)b * N_ + tok) * C_ + c0 + col;
            Th[idx] = h;
            Tl[idx] = f2b(v - b2f(h));
        }
    } else {                            // V: single-bf16 path
        int c0 = (ct - 4) * 16;
        const float* wrow = Wv + (size_t)(c0 + col) * D_;
#pragma unroll
        for (int dc = 0; dc < 8; ++dc) {
            short8 xh, wh;
            cvt8h(xrow + dc * 32 + g * 8, xh);
            cvt8h(wrow + dc * 32 + g * 8, wh);
            acc = __builtin_amdgcn_mfma_f32_16x16x32_bf16(xh, wh, acc, 0, 0, 0);
        }
        float bb = bv[c0 + col];
        ushort4v st;
#pragma unroll
        for (int r = 0; r < 4; ++r) st[r] = f2b(acc[r] + bb);
        *(ushort4v*)(Vm + ((size_t)b * D_ + c0 + col) * N_ + n0 + g * 4) = st;
    }
}

// ---------------------------------------------------------------------------
// Kernel 2: flash attention, in-block KV-split + software pipeline (T14).
// 512 blocks x 8 waves. Wave w owns keys [w*512, (w+1)*512). Per 32-key iter:
// V-loads issue FIRST (latency hides under QK/softmax/LDS), K-frags for the
// NEXT iter prefetch into rotating regs. No-max softmax (scores bounded ~34)
// => cross-wave combine is plain addition via LDS atomicAdd.
// ---------------------------------------------------------------------------
__global__ __launch_bounds__(512, 4) void attn_kernel(
    const unsigned short* __restrict__ Qh, const unsigned short* __restrict__ Ql,
    const unsigned short* __restrict__ Kh, const unsigned short* __restrict__ Kl,
    const unsigned short* __restrict__ Vm, const float* __restrict__ x,
    const float* __restrict__ gamma_p, float* __restrict__ out)
{
    __shared__ unsigned short plds[8][16 * 40];  // per-wave P^T, padded stride 40
    __shared__ float accs[D_ * 17];              // [d][q] stride 17 (bank spread)
    __shared__ float lsum[16];

    int tid  = threadIdx.x;
    int wave = tid >> 6;
    int lane = tid & 63;
    int col = lane & 15, g = lane >> 4;

    int bid = blockIdx.x;                   // 512 % 8 == 0 -> bijective swizzle
    int swz = (bid & 7) * 64 + (bid >> 3);
    int b    = swz >> 8;
    int q0   = (swz & 255) << 4;

    // zero the combine buffers
    for (int i = tid; i < D_ * 17; i += 512) accs[i] = 0.f;
    if (tid < 16) lsum[tid] = 0.f;
    __syncthreads();

    // Q fragments: B[c][q] = Q[q][c], lane col = q, k = g*8+e
    size_t qoff = ((size_t)b * N_ + q0 + col) * C_ + g * 8;
    short8 qfh = *(const short8*)(Qh + qoff);
    short8 qfl = *(const short8*)(Ql + qoff);

    f32x4 acc[16];
#pragma unroll
    for (int t = 0; t < 16; ++t) acc[t] = (f32x4){0.f, 0.f, 0.f, 0.f};
    float l_run = 0.f;

    const unsigned short* kbh = Kh + (size_t)b * N_ * C_;
    const unsigned short* kbl = Kl + (size_t)b * N_ * C_;
    const unsigned short* vb  = Vm + (size_t)b * D_ * N_;
    unsigned short* pw = plds[wave];

    int jbase = wave * (N_ / 8);            // this wave's 512-key chunk

    // pipeline prologue: K frags for it = 0
    size_t k0 = (size_t)(jbase + col) * C_ + g * 8;
    size_t k1 = (size_t)(jbase + 16 + col) * C_ + g * 8;
    short8 kh0 = *(const short8*)(kbh + k0);
    short8 kl0 = *(const short8*)(kbl + k0);
    short8 kh1 = *(const short8*)(kbh + k1);
    short8 kl1 = *(const short8*)(kbl + k1);

    for (int it = 0; it < N_ / 8; it += 32) {
        int j0 = jbase + it;

        // V loads for CURRENT iter, issued first (latency hides under QK+SM)
        short8 vf[16];
        const unsigned short* vrow = vb + (size_t)col * N_ + j0 + g * 8;
#pragma unroll
        for (int t = 0; t < 16; ++t)
            vf[t] = *(const short8*)(vrow + (size_t)t * 16 * N_);

        // K prefetch for NEXT iter (rotating regs; last iter re-reads base)
        int itn = (it + 32 < N_ / 8) ? it + 32 : 0;
        size_t nk0 = (size_t)(jbase + itn + col) * C_ + g * 8;
        size_t nk1 = (size_t)(jbase + itn + 16 + col) * C_ + g * 8;
        short8 nkh0 = *(const short8*)(kbh + nk0);
        short8 nkl0 = *(const short8*)(kbl + nk0);
        short8 nkh1 = *(const short8*)(kbh + nk1);
        short8 nkl1 = *(const short8*)(kbl + nk1);

        // QK^T on current K frags (split-bf16 3-chain): D[key][q]
        f32x4 z = {0.f, 0.f, 0.f, 0.f};
        f32x4 s0 = __builtin_amdgcn_mfma_f32_16x16x32_bf16(kl0, qfh, z, 0, 0, 0);
        s0 = __builtin_amdgcn_mfma_f32_16x16x32_bf16(kh0, qfl, s0, 0, 0, 0);
        s0 = __builtin_amdgcn_mfma_f32_16x16x32_bf16(kh0, qfh, s0, 0, 0, 0);
        f32x4 s1 = __builtin_amdgcn_mfma_f32_16x16x32_bf16(kl1, qfh, z, 0, 0, 0);
        s1 = __builtin_amdgcn_mfma_f32_16x16x32_bf16(kh1, qfl, s1, 0, 0, 0);
        s1 = __builtin_amdgcn_mfma_f32_16x16x32_bf16(kh1, qfh, s1, 0, 0, 0);

        // p = exp(s); scores bounded (~34), clamp is pure safety
        float p0[4], p1[4], sl = 0.f;
#pragma unroll
        for (int r = 0; r < 4; ++r) { p0[r] = __expf(fminf(s0[r], 60.f)); sl += p0[r]; }
#pragma unroll
        for (int r = 0; r < 4; ++r) { p1[r] = __expf(fminf(s1[r], 60.f)); sl += p1[r]; }
        sl += __shfl_xor(sl, 16);
        sl += __shfl_xor(sl, 32);
        l_run += sl;   // per-lane copy of its query's chunk denominator

        // stage P[q][j] in this wave's LDS buffer (padded stride 40)
        ushort4v w0, w1;
#pragma unroll
        for (int r = 0; r < 4; ++r) { w0[r] = f2b(p0[r]); w1[r] = f2b(p1[r]); }
        *(ushort4v*)(pw + col * 40 + g * 4)      = w0;  // keys g*4..+3
        *(ushort4v*)(pw + col * 40 + 16 + g * 4) = w1;  // keys 16+g*4..+3
        asm volatile("s_waitcnt lgkmcnt(0)" ::: "memory");
        __builtin_amdgcn_sched_barrier(0);

        // B-frag for PV: B[j][q] (one ds_read_b128, feeds all 16 MFMAs)
        short8 pf = *(const short8*)(pw + col * 40 + g * 8);
        asm volatile("" ::: "memory");   // next iter's writes stay below

#pragma unroll
        for (int t = 0; t < 16; ++t)
            acc[t] = __builtin_amdgcn_mfma_f32_16x16x32_bf16(vf[t], pf, acc[t], 0, 0, 0);

        kh0 = nkh0; kl0 = nkl0; kh1 = nkh1; kl1 = nkl1;
    }

    // combine partials across waves (plain sums: no-max softmax)
#pragma unroll
    for (int t = 0; t < 16; ++t)
#pragma unroll
        for (int r = 0; r < 4; ++r) {
            int d = t * 16 + g * 4 + r;          // lane holds O[d][q=col]
            atomicAdd(&accs[d * 17 + col], acc[t][r]);
        }
    if (lane < 16) atomicAdd(&lsum[lane], l_run);
    __syncthreads();

    // epilogue: each wave handles 2 queries; lanes cover d (stride 32)
    int qi = wave * 2 + (lane >> 5);   // 0..15
    int li = lane & 31;
    int n = q0 + qi;
    int s = n & (S_ - 1), kk = n >> 6;
    const float* xrow = x + (((size_t)(b * S_ + s)) * K_ + kk) * D_;
    float* orow = out + (((size_t)(b * S_ + s)) * K_ + kk) * D_;
    float inv_l = 1.0f / lsum[qi];
    float gam = gamma_p[0];
#pragma unroll
    for (int k = 0; k < 8; ++k) {
        int d = li + k * 32;
        orow[d] = gam * accs[d * 17 + qi] * inv_l + xrow[d];
    }
}

extern "C" void kernel_launch(void* const* d_in, const int* in_sizes, int n_in,
                              void* d_out, int out_size, void* d_ws, size_t ws_size,
                              hipStream_t stream) {
    const float* x  = (const float*)d_in[0];
    const float* Wq = (const float*)d_in[1];
    const float* bq = (const float*)d_in[2];
    const float* Wk = (const float*)d_in[3];
    const float* bk = (const float*)d_in[4];
    const float* Wv = (const float*)d_in[5];
    const float* bv = (const float*)d_in[6];
    const float* gm = (const float*)d_in[7];

    unsigned short* Qh = (unsigned short*)d_ws;                 // [B][N][C] 512KB
    unsigned short* Ql = Qh + (size_t)B_ * N_ * C_;
    unsigned short* Kh = Ql + (size_t)B_ * N_ * C_;
    unsigned short* Kl = Kh + (size_t)B_ * N_ * C_;
    unsigned short* Vm = Kl + (size_t)B_ * N_ * C_;             // [B][D][N] 4MB
    float* o = (float*)d_out;

    qkv_kernel<<<2560, 256, 0, stream>>>(x, Wq, bq, Wk, bk, Wv, bv,
                                         Qh, Ql, Kh, Kl, Vm);
    attn_kernel<<<512, 512, 0, stream>>>(Qh, Ql, Kh, Kl, Vm, x, gm, o);
}

// Round 6
// 224.021 us; speedup vs baseline: 1.8455x; 1.8455x over previous
//
#include <hip/hip_runtime.h>
#include <stdint.h>
#include <math.h>

using short8   = __attribute__((ext_vector_type(8))) short;
using ushort4v = __attribute__((ext_vector_type(4))) unsigned short;
using f32x4    = __attribute__((ext_vector_type(4))) float;

#define B_ 2
#define S_ 64
#define K_ 64
#define D_ 256
#define C_ 32
#define N_ 4096  /* S_*K_ */

__device__ __forceinline__ float b2f(unsigned short u) {
    unsigned int v = ((unsigned int)u) << 16;
    return __builtin_bit_cast(float, v);
}
__device__ __forceinline__ unsigned short f2b(float f) {   // RNE f32->bf16
    unsigned int x = __builtin_bit_cast(unsigned int, f);
    x += 0x7fffu + ((x >> 16) & 1u);
    return (unsigned short)(x >> 16);
}

// load 8 consecutive f32, produce hi/lo split-bf16 fragments (hi+lo ~ 2^-17 rel)
__device__ __forceinline__ void cvt8(const float* p, short8& hi, short8& lo) {
    f32x4 a = *(const f32x4*)p;
    f32x4 c = *(const f32x4*)(p + 4);
#pragma unroll
    for (int e = 0; e < 4; ++e) {
        unsigned short h0 = f2b(a[e]);
        hi[e]     = (short)h0; lo[e]     = (short)f2b(a[e] - b2f(h0));
        unsigned short h1 = f2b(c[e]);
        hi[e + 4] = (short)h1; lo[e + 4] = (short)f2b(c[e] - b2f(h1));
    }
}
__device__ __forceinline__ void cvt8h(const float* p, short8& hi) {
    f32x4 a = *(const f32x4*)p;
    f32x4 c = *(const f32x4*)(p + 4);
#pragma unroll
    for (int e = 0; e < 4; ++e) {
        hi[e]     = (short)f2b(a[e]);
        hi[e + 4] = (short)f2b(c[e]);
    }
}

// ---------------------------------------------------------------------------
// Kernel 1: QKV projections from f32 x, W. One wave = 16-token x 16-channel.
// ct 0-1 -> Q (hi/lo split), 2-3 -> K (hi/lo), 4-19 -> V (single bf16).
// Q,K stored [B][N][C] bf16 (hi and lo planes); V stored [B][D][N] bf16.
// ---------------------------------------------------------------------------
__global__ __launch_bounds__(256) void qkv_kernel(
    const float* __restrict__ x,
    const float* __restrict__ Wq, const float* __restrict__ bq,
    const float* __restrict__ Wk, const float* __restrict__ bk,
    const float* __restrict__ Wv, const float* __restrict__ bv,
    unsigned short* __restrict__ Qh, unsigned short* __restrict__ Ql,
    unsigned short* __restrict__ Kh, unsigned short* __restrict__ Kl,
    unsigned short* __restrict__ Vm)
{
    int widx = blockIdx.x * 4 + (threadIdx.x >> 6);   // 0..10239
    int lane = threadIdx.x & 63;
    int ttile = widx / 20;        // token tile of 16 (0..511)
    int ct    = widx % 20;        // channel tile
    int b  = ttile >> 8;
    int n0 = (ttile & 255) << 4;
    int col = lane & 15, g = lane >> 4;

    int n = n0 + col;
    int s = n & (S_ - 1), kk = n >> 6;
    const float* xrow = x + (((size_t)(b * S_ + s)) * K_ + kk) * D_;

    f32x4 acc = {0.f, 0.f, 0.f, 0.f};

    if (ct < 4) {                       // Q or K: hi/lo split path
        const float* W; const float* bias; int c0;
        if (ct < 2) { W = Wq; bias = bq; c0 = ct * 16; }
        else        { W = Wk; bias = bk; c0 = (ct - 2) * 16; }
        const float* wrow = W + (size_t)(c0 + col) * D_;
#pragma unroll
        for (int dc = 0; dc < 8; ++dc) {
            short8 xh, xl, wh, wl;
            cvt8(xrow + dc * 32 + g * 8, xh, xl);
            cvt8(wrow + dc * 32 + g * 8, wh, wl);
            acc = __builtin_amdgcn_mfma_f32_16x16x32_bf16(xl, wh, acc, 0, 0, 0);
            acc = __builtin_amdgcn_mfma_f32_16x16x32_bf16(xh, wl, acc, 0, 0, 0);
            acc = __builtin_amdgcn_mfma_f32_16x16x32_bf16(xh, wh, acc, 0, 0, 0);
        }
        float bb = bias[c0 + col];
        unsigned short* Th = (ct < 2) ? Qh : Kh;
        unsigned short* Tl = (ct < 2) ? Ql : Kl;
#pragma unroll
        for (int r = 0; r < 4; ++r) {
            int tok = n0 + g * 4 + r;
            float v = acc[r] + bb;
            unsigned short h = f2b(v);
            size_t idx = ((size_t)b * N_ + tok) * C_ + c0 + col;
            Th[idx] = h;
            Tl[idx] = f2b(v - b2f(h));
        }
    } else {                            // V: single-bf16 path
        int c0 = (ct - 4) * 16;
        const float* wrow = Wv + (size_t)(c0 + col) * D_;
#pragma unroll
        for (int dc = 0; dc < 8; ++dc) {
            short8 xh, wh;
            cvt8h(xrow + dc * 32 + g * 8, xh);
            cvt8h(wrow + dc * 32 + g * 8, wh);
            acc = __builtin_amdgcn_mfma_f32_16x16x32_bf16(xh, wh, acc, 0, 0, 0);
        }
        float bb = bv[c0 + col];
        ushort4v st;
#pragma unroll
        for (int r = 0; r < 4; ++r) st[r] = f2b(acc[r] + bb);
        *(ushort4v*)(Vm + ((size_t)b * D_ + c0 + col) * N_ + n0 + g * 4) = st;
    }
}

// ---------------------------------------------------------------------------
// Kernel 2: flash attention, pair-split to fit the 128-reg/wave budget.
// 512 blocks x 8 waves = 4 pairs. Pair p owns keys [p*1024,(p+1)*1024);
// within a pair, wave h owns d-half [h*128, h*128+128) for PV (acc[8]+vf[8]
// = 64 regs instead of 128 -> no scratch spill) and computes QK^T+softmax on
// iterations with (it&1)==h. P double-buffered per pair in LDS; one
// __syncthreads per 32-key iteration hands P to both halves. No-max softmax
// (scores bounded ~34) => cross-wave combine is plain addition (atomicAdd).
// ---------------------------------------------------------------------------
__global__ __launch_bounds__(512, 4) void attn_kernel(
    const unsigned short* __restrict__ Qh, const unsigned short* __restrict__ Ql,
    const unsigned short* __restrict__ Kh, const unsigned short* __restrict__ Kl,
    const unsigned short* __restrict__ Vm, const float* __restrict__ x,
    const float* __restrict__ gamma_p, float* __restrict__ out)
{
    __shared__ unsigned short plds[4][2][16 * 40];  // [pair][buf] P^T, stride 40
    __shared__ float accs[D_ * 17];                 // [d][q] stride 17
    __shared__ float lsum[16];

    int tid  = threadIdx.x;
    int wave = tid >> 6;
    int lane = tid & 63;
    int col = lane & 15, g = lane >> 4;
    int pair = wave >> 1, h = wave & 1;
    int dbase = h * 128;
    int jbase = pair * (N_ / 4);

    int bid = blockIdx.x;                   // 512 % 8 == 0 -> bijective swizzle
    int swz = (bid & 7) * 64 + (bid >> 3);
    int b    = swz >> 8;
    int q0   = (swz & 255) << 4;

    // zero the combine buffers
    for (int i = tid; i < D_ * 17; i += 512) accs[i] = 0.f;
    if (tid < 16) lsum[tid] = 0.f;
    __syncthreads();

    // Q fragments: B[c][q] = Q[q][c], lane col = q, k = g*8+e
    size_t qoff = ((size_t)b * N_ + q0 + col) * C_ + g * 8;
    short8 qfh = *(const short8*)(Qh + qoff);
    short8 qfl = *(const short8*)(Ql + qoff);

    f32x4 acc[8];
#pragma unroll
    for (int t = 0; t < 8; ++t) acc[t] = (f32x4){0.f, 0.f, 0.f, 0.f};
    float l_run = 0.f;

    const unsigned short* kbh = Kh + (size_t)b * N_ * C_;
    const unsigned short* kbl = Kl + (size_t)b * N_ * C_;
    const unsigned short* vb  = Vm + (size_t)b * D_ * N_;
    unsigned short* pown = plds[pair][h];   // this wave's write buffer

    for (int it = 0; it < 32; ++it) {
        int j0 = jbase + it * 32;

        // V preload for this iter's 32 keys, own d-half (8 frags = 32 VGPR)
        short8 vf[8];
        const unsigned short* vcol = vb + (size_t)(dbase + col) * N_ + j0 + g * 8;
#pragma unroll
        for (int t = 0; t < 8; ++t)
            vf[t] = *(const short8*)(vcol + (size_t)t * 16 * N_);

        if ((it & 1) == h) {   // my turn: QK^T + softmax + P write (wave-uniform)
            size_t k0 = (size_t)(j0 + col) * C_ + g * 8;
            size_t k1 = (size_t)(j0 + 16 + col) * C_ + g * 8;
            short8 kh0 = *(const short8*)(kbh + k0);
            short8 kl0 = *(const short8*)(kbl + k0);
            short8 kh1 = *(const short8*)(kbh + k1);
            short8 kl1 = *(const short8*)(kbl + k1);

            f32x4 z = {0.f, 0.f, 0.f, 0.f};
            f32x4 s0 = __builtin_amdgcn_mfma_f32_16x16x32_bf16(kl0, qfh, z, 0, 0, 0);
            s0 = __builtin_amdgcn_mfma_f32_16x16x32_bf16(kh0, qfl, s0, 0, 0, 0);
            s0 = __builtin_amdgcn_mfma_f32_16x16x32_bf16(kh0, qfh, s0, 0, 0, 0);
            f32x4 s1 = __builtin_amdgcn_mfma_f32_16x16x32_bf16(kl1, qfh, z, 0, 0, 0);
            s1 = __builtin_amdgcn_mfma_f32_16x16x32_bf16(kh1, qfl, s1, 0, 0, 0);
            s1 = __builtin_amdgcn_mfma_f32_16x16x32_bf16(kh1, qfh, s1, 0, 0, 0);

            float p0[4], p1[4], sl = 0.f;
#pragma unroll
            for (int r = 0; r < 4; ++r) { p0[r] = __expf(fminf(s0[r], 60.f)); sl += p0[r]; }
#pragma unroll
            for (int r = 0; r < 4; ++r) { p1[r] = __expf(fminf(s1[r], 60.f)); sl += p1[r]; }
            sl += __shfl_xor(sl, 16);
            sl += __shfl_xor(sl, 32);
            l_run += sl;   // only the QK owner counts these keys

            ushort4v w0, w1;
#pragma unroll
            for (int r = 0; r < 4; ++r) { w0[r] = f2b(p0[r]); w1[r] = f2b(p1[r]); }
            *(ushort4v*)(pown + col * 40 + g * 4)      = w0;  // keys g*4..+3
            *(ushort4v*)(pown + col * 40 + 16 + g * 4) = w1;  // keys 16+g*4..+3
        }
        __syncthreads();   // P visible to both halves of every pair

        // B-frag for PV from the iteration's owner buffer
        short8 pf = *(const short8*)(plds[pair][it & 1] + col * 40 + g * 8);

#pragma unroll
        for (int t = 0; t < 8; ++t)
            acc[t] = __builtin_amdgcn_mfma_f32_16x16x32_bf16(vf[t], pf, acc[t], 0, 0, 0);
    }

    // combine partials across waves (plain sums: no-max softmax)
#pragma unroll
    for (int t = 0; t < 8; ++t)
#pragma unroll
        for (int r = 0; r < 4; ++r) {
            int d = dbase + t * 16 + g * 4 + r;   // lane holds O[d][q=col]
            atomicAdd(&accs[d * 17 + col], acc[t][r]);
        }
    if (lane < 16) atomicAdd(&lsum[lane], l_run);
    __syncthreads();

    // epilogue: each wave handles 2 queries; lanes cover d (stride 32)
    int qi = wave * 2 + (lane >> 5);   // 0..15
    int li = lane & 31;
    int n = q0 + qi;
    int s = n & (S_ - 1), kk = n >> 6;
    const float* xrow = x + (((size_t)(b * S_ + s)) * K_ + kk) * D_;
    float* orow = out + (((size_t)(b * S_ + s)) * K_ + kk) * D_;
    float inv_l = 1.0f / lsum[qi];
    float gam = gamma_p[0];
#pragma unroll
    for (int k = 0; k < 8; ++k) {
        int d = li + k * 32;
        orow[d] = gam * accs[d * 17 + qi] * inv_l + xrow[d];
    }
}

extern "C" void kernel_launch(void* const* d_in, const int* in_sizes, int n_in,
                              void* d_out, int out_size, void* d_ws, size_t ws_size,
                              hipStream_t stream) {
    const float* x  = (const float*)d_in[0];
    const float* Wq = (const float*)d_in[1];
    const float* bq = (const float*)d_in[2];
    const float* Wk = (const float*)d_in[3];
    const float* bk = (const float*)d_in[4];
    const float* Wv = (const float*)d_in[5];
    const float* bv = (const float*)d_in[6];
    const float* gm = (const float*)d_in[7];

    unsigned short* Qh = (unsigned short*)d_ws;                 // [B][N][C] 512KB
    unsigned short* Ql = Qh + (size_t)B_ * N_ * C_;
    unsigned short* Kh = Ql + (size_t)B_ * N_ * C_;
    unsigned short* Kl = Kh + (size_t)B_ * N_ * C_;
    unsigned short* Vm = Kl + (size_t)B_ * N_ * C_;             // [B][D][N] 4MB
    float* o = (float*)d_out;

    qkv_kernel<<<2560, 256, 0, stream>>>(x, Wq, bq, Wk, bk, Wv, bv,
                                         Qh, Ql, Kh, Kl, Vm);
    attn_kernel<<<512, 512, 0, stream>>>(Qh, Ql, Kh, Kl, Vm, x, gm, o);
}

// Round 7
// 168.888 us; speedup vs baseline: 2.4480x; 1.3264x over previous
//
#include <hip/hip_runtime.h>
#include <stdint.h>
#include <math.h>

using short8   = __attribute__((ext_vector_type(8))) short;
using ushort4v = __attribute__((ext_vector_type(4))) unsigned short;
using f32x4    = __attribute__((ext_vector_type(4))) float;

#define B_ 2
#define S_ 64
#define K_ 64
#define D_ 256
#define C_ 32
#define N_ 4096  /* S_*K_ */

__device__ __forceinline__ float b2f(unsigned short u) {
    unsigned int v = ((unsigned int)u) << 16;
    return __builtin_bit_cast(float, v);
}
__device__ __forceinline__ unsigned short f2b(float f) {   // RNE f32->bf16
    unsigned int x = __builtin_bit_cast(unsigned int, f);
    x += 0x7fffu + ((x >> 16) & 1u);
    return (unsigned short)(x >> 16);
}

// load 8 consecutive f32, produce hi/lo split-bf16 fragments (hi+lo ~ 2^-17 rel)
__device__ __forceinline__ void cvt8(const float* p, short8& hi, short8& lo) {
    f32x4 a = *(const f32x4*)p;
    f32x4 c = *(const f32x4*)(p + 4);
#pragma unroll
    for (int e = 0; e < 4; ++e) {
        unsigned short h0 = f2b(a[e]);
        hi[e]     = (short)h0; lo[e]     = (short)f2b(a[e] - b2f(h0));
        unsigned short h1 = f2b(c[e]);
        hi[e + 4] = (short)h1; lo[e + 4] = (short)f2b(c[e] - b2f(h1));
    }
}
__device__ __forceinline__ void cvt8h(const float* p, short8& hi) {
    f32x4 a = *(const f32x4*)p;
    f32x4 c = *(const f32x4*)(p + 4);
#pragma unroll
    for (int e = 0; e < 4; ++e) {
        hi[e]     = (short)f2b(a[e]);
        hi[e + 4] = (short)f2b(c[e]);
    }
}

// ---------------------------------------------------------------------------
// Kernel 1: QKV projections from f32 x, W. One wave = 16-token x 16-channel.
// ct 0-1 -> Q (hi/lo split), 2-3 -> K (hi/lo), 4-19 -> V (single bf16).
// Q,K stored [B][N][C] bf16 (hi/lo planes).
// V stored chunk-interleaved [B][N/32][D][32] bf16: per 32-key chunk all d
// contiguous -> attn reads one sequential 16 KB block per iteration (kills
// the 8 KB power-of-2 stride L2-channel aliasing of the old [B][D][N]).
// ---------------------------------------------------------------------------
__global__ __launch_bounds__(256) void qkv_kernel(
    const float* __restrict__ x,
    const float* __restrict__ Wq, const float* __restrict__ bq,
    const float* __restrict__ Wk, const float* __restrict__ bk,
    const float* __restrict__ Wv, const float* __restrict__ bv,
    unsigned short* __restrict__ Qh, unsigned short* __restrict__ Ql,
    unsigned short* __restrict__ Kh, unsigned short* __restrict__ Kl,
    unsigned short* __restrict__ Vm)
{
    int widx = blockIdx.x * 4 + (threadIdx.x >> 6);   // 0..10239
    int lane = threadIdx.x & 63;
    int ttile = widx / 20;        // token tile of 16 (0..511)
    int ct    = widx % 20;        // channel tile
    int b  = ttile >> 8;
    int n0 = (ttile & 255) << 4;
    int col = lane & 15, g = lane >> 4;

    int n = n0 + col;
    int s = n & (S_ - 1), kk = n >> 6;
    const float* xrow = x + (((size_t)(b * S_ + s)) * K_ + kk) * D_;

    f32x4 acc = {0.f, 0.f, 0.f, 0.f};

    if (ct < 4) {                       // Q or K: hi/lo split path
        const float* W; const float* bias; int c0;
        if (ct < 2) { W = Wq; bias = bq; c0 = ct * 16; }
        else        { W = Wk; bias = bk; c0 = (ct - 2) * 16; }
        const float* wrow = W + (size_t)(c0 + col) * D_;
#pragma unroll
        for (int dc = 0; dc < 8; ++dc) {
            short8 xh, xl, wh, wl;
            cvt8(xrow + dc * 32 + g * 8, xh, xl);
            cvt8(wrow + dc * 32 + g * 8, wh, wl);
            acc = __builtin_amdgcn_mfma_f32_16x16x32_bf16(xl, wh, acc, 0, 0, 0);
            acc = __builtin_amdgcn_mfma_f32_16x16x32_bf16(xh, wl, acc, 0, 0, 0);
            acc = __builtin_amdgcn_mfma_f32_16x16x32_bf16(xh, wh, acc, 0, 0, 0);
        }
        float bb = bias[c0 + col];
        unsigned short* Th = (ct < 2) ? Qh : Kh;
        unsigned short* Tl = (ct < 2) ? Ql : Kl;
#pragma unroll
        for (int r = 0; r < 4; ++r) {
            int tok = n0 + g * 4 + r;
            float v = acc[r] + bb;
            unsigned short h = f2b(v);
            size_t idx = ((size_t)b * N_ + tok) * C_ + c0 + col;
            Th[idx] = h;
            Tl[idx] = f2b(v - b2f(h));
        }
    } else {                            // V: single-bf16 path
        int c0 = (ct - 4) * 16;
        const float* wrow = Wv + (size_t)(c0 + col) * D_;
#pragma unroll
        for (int dc = 0; dc < 8; ++dc) {
            short8 xh, wh;
            cvt8h(xrow + dc * 32 + g * 8, xh);
            cvt8h(wrow + dc * 32 + g * 8, wh);
            acc = __builtin_amdgcn_mfma_f32_16x16x32_bf16(xh, wh, acc, 0, 0, 0);
        }
        float bb = bv[c0 + col];
        ushort4v st;
#pragma unroll
        for (int r = 0; r < 4; ++r) st[r] = f2b(acc[r] + bb);
        // chunk-interleaved store: tokens tok0..tok0+3 share chunk tok0>>5
        int tok0 = n0 + g * 4;
        size_t vaddr = (((size_t)b * (N_ / 32) + (tok0 >> 5)) * D_ + c0 + col) * 32
                     + (tok0 & 31);
        *(ushort4v*)(Vm + vaddr) = st;
    }
}

// ---------------------------------------------------------------------------
// Kernel 2: flash attention, pair-split (R6 structure, V layout changed).
// 512 blocks x 8 waves = 4 pairs. Pair p owns keys [p*1024,(p+1)*1024);
// wave h of a pair owns d-half [h*128,h*128+128) for PV and does QK^T+softmax
// on iterations with (it&1)==h. P double-buffered per pair in LDS; one
// __syncthreads per 32-key iteration. No-max softmax (scores bounded ~34) =>
// cross-wave combine is plain addition (LDS atomicAdd).
// V reads: one contiguous 16 KB chunk per iteration, each short8 load is a
// perfectly-coalesced contiguous 1 KB wave transaction.
// ---------------------------------------------------------------------------
__global__ __launch_bounds__(512, 4) void attn_kernel(
    const unsigned short* __restrict__ Qh, const unsigned short* __restrict__ Ql,
    const unsigned short* __restrict__ Kh, const unsigned short* __restrict__ Kl,
    const unsigned short* __restrict__ Vm, const float* __restrict__ x,
    const float* __restrict__ gamma_p, float* __restrict__ out)
{
    __shared__ unsigned short plds[4][2][16 * 40];  // [pair][buf] P^T, stride 40
    __shared__ float accs[D_ * 17];                 // [d][q] stride 17
    __shared__ float lsum[16];

    int tid  = threadIdx.x;
    int wave = tid >> 6;
    int lane = tid & 63;
    int col = lane & 15, g = lane >> 4;
    int pair = wave >> 1, h = wave & 1;
    int dbase = h * 128;
    int jbase = pair * (N_ / 4);

    int bid = blockIdx.x;                   // 512 % 8 == 0 -> bijective swizzle
    int swz = (bid & 7) * 64 + (bid >> 3);
    int b    = swz >> 8;
    int q0   = (swz & 255) << 4;

    // zero the combine buffers
    for (int i = tid; i < D_ * 17; i += 512) accs[i] = 0.f;
    if (tid < 16) lsum[tid] = 0.f;
    __syncthreads();

    // Q fragments: B[c][q] = Q[q][c], lane col = q, k = g*8+e
    size_t qoff = ((size_t)b * N_ + q0 + col) * C_ + g * 8;
    short8 qfh = *(const short8*)(Qh + qoff);
    short8 qfl = *(const short8*)(Ql + qoff);

    f32x4 acc[8];
#pragma unroll
    for (int t = 0; t < 8; ++t) acc[t] = (f32x4){0.f, 0.f, 0.f, 0.f};
    float l_run = 0.f;

    const unsigned short* kbh = Kh + (size_t)b * N_ * C_;
    const unsigned short* kbl = Kl + (size_t)b * N_ * C_;
    const unsigned short* vb  = Vm + (size_t)b * N_ * D_;   // [N/32][D][32]
    unsigned short* pown = plds[pair][h];   // this wave's write buffer

    for (int it = 0; it < 32; ++it) {
        int j0 = jbase + it * 32;

        // V preload, own d-half: 8 coalesced 1KB loads inside one 16KB chunk
        short8 vf[8];
        const unsigned short* vch = vb + (size_t)(j0 >> 5) * (D_ * 32)
                                  + (size_t)(dbase + col) * 32 + g * 8;
#pragma unroll
        for (int t = 0; t < 8; ++t)
            vf[t] = *(const short8*)(vch + t * (16 * 32));

        if ((it & 1) == h) {   // my turn: QK^T + softmax + P write (wave-uniform)
            size_t k0 = (size_t)(j0 + col) * C_ + g * 8;
            size_t k1 = (size_t)(j0 + 16 + col) * C_ + g * 8;
            short8 kh0 = *(const short8*)(kbh + k0);
            short8 kl0 = *(const short8*)(kbl + k0);
            short8 kh1 = *(const short8*)(kbh + k1);
            short8 kl1 = *(const short8*)(kbl + k1);

            f32x4 z = {0.f, 0.f, 0.f, 0.f};
            f32x4 s0 = __builtin_amdgcn_mfma_f32_16x16x32_bf16(kl0, qfh, z, 0, 0, 0);
            s0 = __builtin_amdgcn_mfma_f32_16x16x32_bf16(kh0, qfl, s0, 0, 0, 0);
            s0 = __builtin_amdgcn_mfma_f32_16x16x32_bf16(kh0, qfh, s0, 0, 0, 0);
            f32x4 s1 = __builtin_amdgcn_mfma_f32_16x16x32_bf16(kl1, qfh, z, 0, 0, 0);
            s1 = __builtin_amdgcn_mfma_f32_16x16x32_bf16(kh1, qfl, s1, 0, 0, 0);
            s1 = __builtin_amdgcn_mfma_f32_16x16x32_bf16(kh1, qfh, s1, 0, 0, 0);

            float p0[4], p1[4], sl = 0.f;
#pragma unroll
            for (int r = 0; r < 4; ++r) { p0[r] = __expf(fminf(s0[r], 60.f)); sl += p0[r]; }
#pragma unroll
            for (int r = 0; r < 4; ++r) { p1[r] = __expf(fminf(s1[r], 60.f)); sl += p1[r]; }
            sl += __shfl_xor(sl, 16);
            sl += __shfl_xor(sl, 32);
            l_run += sl;   // only the QK owner counts these keys

            ushort4v w0, w1;
#pragma unroll
            for (int r = 0; r < 4; ++r) { w0[r] = f2b(p0[r]); w1[r] = f2b(p1[r]); }
            *(ushort4v*)(pown + col * 40 + g * 4)      = w0;  // keys g*4..+3
            *(ushort4v*)(pown + col * 40 + 16 + g * 4) = w1;  // keys 16+g*4..+3
        }
        __syncthreads();   // P visible to both halves of every pair

        // B-frag for PV from the iteration's owner buffer
        short8 pf = *(const short8*)(plds[pair][it & 1] + col * 40 + g * 8);

#pragma unroll
        for (int t = 0; t < 8; ++t)
            acc[t] = __builtin_amdgcn_mfma_f32_16x16x32_bf16(vf[t], pf, acc[t], 0, 0, 0);
    }

    // combine partials across waves (plain sums: no-max softmax)
#pragma unroll
    for (int t = 0; t < 8; ++t)
#pragma unroll
        for (int r = 0; r < 4; ++r) {
            int d = dbase + t * 16 + g * 4 + r;   // lane holds O[d][q=col]
            atomicAdd(&accs[d * 17 + col], acc[t][r]);
        }
    if (lane < 16) atomicAdd(&lsum[lane], l_run);
    __syncthreads();

    // epilogue: each wave handles 2 queries; lanes cover d (stride 32)
    int qi = wave * 2 + (lane >> 5);   // 0..15
    int li = lane & 31;
    int n = q0 + qi;
    int s = n & (S_ - 1), kk = n >> 6;
    const float* xrow = x + (((size_t)(b * S_ + s)) * K_ + kk) * D_;
    float* orow = out + (((size_t)(b * S_ + s)) * K_ + kk) * D_;
    float inv_l = 1.0f / lsum[qi];
    float gam = gamma_p[0];
#pragma unroll
    for (int k = 0; k < 8; ++k) {
        int d = li + k * 32;
        orow[d] = gam * accs[d * 17 + qi] * inv_l + xrow[d];
    }
}

extern "C" void kernel_launch(void* const* d_in, const int* in_sizes, int n_in,
                              void* d_out, int out_size, void* d_ws, size_t ws_size,
                              hipStream_t stream) {
    const float* x  = (const float*)d_in[0];
    const float* Wq = (const float*)d_in[1];
    const float* bq = (const float*)d_in[2];
    const float* Wk = (const float*)d_in[3];
    const float* bk = (const float*)d_in[4];
    const float* Wv = (const float*)d_in[5];
    const float* bv = (const float*)d_in[6];
    const float* gm = (const float*)d_in[7];

    unsigned short* Qh = (unsigned short*)d_ws;                 // [B][N][C] 512KB
    unsigned short* Ql = Qh + (size_t)B_ * N_ * C_;
    unsigned short* Kh = Ql + (size_t)B_ * N_ * C_;
    unsigned short* Kl = Kh + (size_t)B_ * N_ * C_;
    unsigned short* Vm = Kl + (size_t)B_ * N_ * C_;   // [B][N/32][D][32] 4MB
    float* o = (float*)d_out;

    qkv_kernel<<<2560, 256, 0, stream>>>(x, Wq, bq, Wk, bk, Wv, bv,
                                         Qh, Ql, Kh, Kl, Vm);
    attn_kernel<<<512, 512, 0, stream>>>(Qh, Ql, Kh, Kl, Vm, x, gm, o);
}

// Round 8
// 156.622 us; speedup vs baseline: 2.6397x; 1.0783x over previous
//
#include <hip/hip_runtime.h>
#include <stdint.h>
#include <math.h>

using short8   = __attribute__((ext_vector_type(8))) short;
using ushort4v = __attribute__((ext_vector_type(4))) unsigned short;
using f32x4    = __attribute__((ext_vector_type(4))) float;

#define B_ 2
#define S_ 64
#define K_ 64
#define D_ 256
#define C_ 32
#define N_ 4096  /* S_*K_ */

__device__ __forceinline__ float b2f(unsigned short u) {
    unsigned int v = ((unsigned int)u) << 16;
    return __builtin_bit_cast(float, v);
}
__device__ __forceinline__ unsigned short f2b(float f) {   // RNE f32->bf16
    unsigned int x = __builtin_bit_cast(unsigned int, f);
    x += 0x7fffu + ((x >> 16) & 1u);
    return (unsigned short)(x >> 16);
}

// load 8 consecutive f32, produce hi/lo split-bf16 fragments (hi+lo ~ 2^-17 rel)
__device__ __forceinline__ void cvt8(const float* p, short8& hi, short8& lo) {
    f32x4 a = *(const f32x4*)p;
    f32x4 c = *(const f32x4*)(p + 4);
#pragma unroll
    for (int e = 0; e < 4; ++e) {
        unsigned short h0 = f2b(a[e]);
        hi[e]     = (short)h0; lo[e]     = (short)f2b(a[e] - b2f(h0));
        unsigned short h1 = f2b(c[e]);
        hi[e + 4] = (short)h1; lo[e + 4] = (short)f2b(c[e] - b2f(h1));
    }
}
__device__ __forceinline__ void cvt8h(const float* p, short8& hi) {
    f32x4 a = *(const f32x4*)p;
    f32x4 c = *(const f32x4*)(p + 4);
#pragma unroll
    for (int e = 0; e < 4; ++e) {
        hi[e]     = (short)f2b(a[e]);
        hi[e + 4] = (short)f2b(c[e]);
    }
}

// ---------------------------------------------------------------------------
// Kernel 1: QKV projections from f32 x, W. One wave = 16-token x 16-channel.
// ct 0-1 -> Q (hi/lo split), 2-3 -> K (hi/lo), 4-19 -> V (single bf16).
// Q,K stored [B][N][C] bf16 (hi/lo planes). V stored chunk-interleaved
// [B][N/32][D][32] bf16 (one 16 KB contiguous block per 32-key chunk).
// ---------------------------------------------------------------------------
__global__ __launch_bounds__(256) void qkv_kernel(
    const float* __restrict__ x,
    const float* __restrict__ Wq, const float* __restrict__ bq,
    const float* __restrict__ Wk, const float* __restrict__ bk,
    const float* __restrict__ Wv, const float* __restrict__ bv,
    unsigned short* __restrict__ Qh, unsigned short* __restrict__ Ql,
    unsigned short* __restrict__ Kh, unsigned short* __restrict__ Kl,
    unsigned short* __restrict__ Vm)
{
    int widx = blockIdx.x * 4 + (threadIdx.x >> 6);   // 0..10239
    int lane = threadIdx.x & 63;
    int ttile = widx / 20;        // token tile of 16 (0..511)
    int ct    = widx % 20;        // channel tile
    int b  = ttile >> 8;
    int n0 = (ttile & 255) << 4;
    int col = lane & 15, g = lane >> 4;

    int n = n0 + col;
    int s = n & (S_ - 1), kk = n >> 6;
    const float* xrow = x + (((size_t)(b * S_ + s)) * K_ + kk) * D_;

    f32x4 acc = {0.f, 0.f, 0.f, 0.f};

    if (ct < 4) {                       // Q or K: hi/lo split path
        const float* W; const float* bias; int c0;
        if (ct < 2) { W = Wq; bias = bq; c0 = ct * 16; }
        else        { W = Wk; bias = bk; c0 = (ct - 2) * 16; }
        const float* wrow = W + (size_t)(c0 + col) * D_;
#pragma unroll
        for (int dc = 0; dc < 8; ++dc) {
            short8 xh, xl, wh, wl;
            cvt8(xrow + dc * 32 + g * 8, xh, xl);
            cvt8(wrow + dc * 32 + g * 8, wh, wl);
            acc = __builtin_amdgcn_mfma_f32_16x16x32_bf16(xl, wh, acc, 0, 0, 0);
            acc = __builtin_amdgcn_mfma_f32_16x16x32_bf16(xh, wl, acc, 0, 0, 0);
            acc = __builtin_amdgcn_mfma_f32_16x16x32_bf16(xh, wh, acc, 0, 0, 0);
        }
        float bb = bias[c0 + col];
        unsigned short* Th = (ct < 2) ? Qh : Kh;
        unsigned short* Tl = (ct < 2) ? Ql : Kl;
#pragma unroll
        for (int r = 0; r < 4; ++r) {
            int tok = n0 + g * 4 + r;
            float v = acc[r] + bb;
            unsigned short h = f2b(v);
            size_t idx = ((size_t)b * N_ + tok) * C_ + c0 + col;
            Th[idx] = h;
            Tl[idx] = f2b(v - b2f(h));
        }
    } else {                            // V: single-bf16 path
        int c0 = (ct - 4) * 16;
        const float* wrow = Wv + (size_t)(c0 + col) * D_;
#pragma unroll
        for (int dc = 0; dc < 8; ++dc) {
            short8 xh, wh;
            cvt8h(xrow + dc * 32 + g * 8, xh);
            cvt8h(wrow + dc * 32 + g * 8, wh);
            acc = __builtin_amdgcn_mfma_f32_16x16x32_bf16(xh, wh, acc, 0, 0, 0);
        }
        float bb = bv[c0 + col];
        ushort4v st;
#pragma unroll
        for (int r = 0; r < 4; ++r) st[r] = f2b(acc[r] + bb);
        int tok0 = n0 + g * 4;
        size_t vaddr = (((size_t)b * (N_ / 32) + (tok0 >> 5)) * D_ + c0 + col) * 32
                     + (tok0 & 31);
        *(ushort4v*)(Vm + vaddr) = st;
    }
}

// ---------------------------------------------------------------------------
// Kernel 2: flash attention, 32-query blocks with producer-consumer skew.
// 256 blocks x 8 waves = 2 key-ranges x 4 d-quarters. Range r covers keys
// [r*2048,(r+1)*2048) in 64 iters of 32. During iter it, the rotating owner
// (dq == (it+1)&3) computes P(it+1) into LDS buf (it+1)&1 while ALL waves
// run PV(it) from buf it&1 (written last iter) -> QK/softmax off the PV
// critical path, one __syncthreads per iter, no same-iter LDS handoff.
// V prefetched one iter ahead into registers (256-reg cap: no spill).
// No-max softmax (scores bounded ~34) => partials combine by plain addition.
// ---------------------------------------------------------------------------
__global__ __launch_bounds__(512, 2) void attn_kernel(
    const unsigned short* __restrict__ Qh, const unsigned short* __restrict__ Ql,
    const unsigned short* __restrict__ Kh, const unsigned short* __restrict__ Kl,
    const unsigned short* __restrict__ Vm, const float* __restrict__ x,
    const float* __restrict__ gamma_p, float* __restrict__ out)
{
    __shared__ unsigned short plds[2][2][32 * 40];  // [range][buf] P[q][j], pad 40
    __shared__ float accs[D_ * 33];                 // [d][q] stride 33
    __shared__ float lsum[32];

    int tid  = threadIdx.x;
    int wave = tid >> 6;
    int lane = tid & 63;
    int col = lane & 15, g = lane >> 4;
    int rng = wave >> 2;          // key-range 0..1
    int dq  = wave & 3;           // d-quarter 0..3
    int rbase = rng * (N_ / 2);

    int bid = blockIdx.x;                   // 256 % 8 == 0 -> bijective swizzle
    int swz = (bid & 7) * 32 + (bid >> 3);
    int b    = swz >> 7;
    int q0   = (swz & 127) << 5;            // 32 queries per block

    for (int i = tid; i < D_ * 33; i += 512) accs[i] = 0.f;
    if (tid < 32) lsum[tid] = 0.f;

    // Q fragments for both q-subtiles (hi/lo planes)
    size_t qoff0 = ((size_t)b * N_ + q0 + col) * C_ + g * 8;
    size_t qoff1 = ((size_t)b * N_ + q0 + 16 + col) * C_ + g * 8;
    short8 qfh0 = *(const short8*)(Qh + qoff0);
    short8 qfl0 = *(const short8*)(Ql + qoff0);
    short8 qfh1 = *(const short8*)(Qh + qoff1);
    short8 qfl1 = *(const short8*)(Ql + qoff1);

    f32x4 acc[2][4];
#pragma unroll
    for (int qs = 0; qs < 2; ++qs)
#pragma unroll
        for (int dt = 0; dt < 4; ++dt) acc[qs][dt] = (f32x4){0.f, 0.f, 0.f, 0.f};
    float l_run0 = 0.f, l_run1 = 0.f;

    const unsigned short* kbh = Kh + (size_t)b * N_ * C_;
    const unsigned short* kbl = Kl + (size_t)b * N_ * C_;
    const unsigned short* vb  = Vm + (size_t)b * N_ * D_;   // [N/32][D][32]
    unsigned short* pw = &plds[rng][0][0];                  // buf stride 32*40

    // produce P(jt) into buf jt&1 for this range (called by the owner wave)
    auto produce = [&](int jt) {
        int j0 = rbase + jt * 32;
        unsigned short* pb = pw + (jt & 1) * (32 * 40);
#pragma unroll
        for (int ks = 0; ks < 2; ++ks) {
            size_t ko = (size_t)(j0 + ks * 16 + col) * C_ + g * 8;
            short8 kh = *(const short8*)(kbh + ko);
            short8 kl = *(const short8*)(kbl + ko);
            f32x4 z = {0.f, 0.f, 0.f, 0.f};
            f32x4 s0 = __builtin_amdgcn_mfma_f32_16x16x32_bf16(kl, qfh0, z, 0, 0, 0);
            s0 = __builtin_amdgcn_mfma_f32_16x16x32_bf16(kh, qfl0, s0, 0, 0, 0);
            s0 = __builtin_amdgcn_mfma_f32_16x16x32_bf16(kh, qfh0, s0, 0, 0, 0);
            f32x4 s1 = __builtin_amdgcn_mfma_f32_16x16x32_bf16(kl, qfh1, z, 0, 0, 0);
            s1 = __builtin_amdgcn_mfma_f32_16x16x32_bf16(kh, qfl1, s1, 0, 0, 0);
            s1 = __builtin_amdgcn_mfma_f32_16x16x32_bf16(kh, qfh1, s1, 0, 0, 0);

            float p0[4], p1[4], sl0 = 0.f, sl1 = 0.f;
#pragma unroll
            for (int r = 0; r < 4; ++r) { p0[r] = __expf(fminf(s0[r], 60.f)); sl0 += p0[r]; }
#pragma unroll
            for (int r = 0; r < 4; ++r) { p1[r] = __expf(fminf(s1[r], 60.f)); sl1 += p1[r]; }
            sl0 += __shfl_xor(sl0, 16); sl0 += __shfl_xor(sl0, 32);
            sl1 += __shfl_xor(sl1, 16); sl1 += __shfl_xor(sl1, 32);
            l_run0 += sl0; l_run1 += sl1;

            ushort4v w0, w1;
#pragma unroll
            for (int r = 0; r < 4; ++r) { w0[r] = f2b(p0[r]); w1[r] = f2b(p1[r]); }
            *(ushort4v*)(pb + col * 40 + ks * 16 + g * 4)        = w0;  // qsub0
            *(ushort4v*)(pb + (16 + col) * 40 + ks * 16 + g * 4) = w1;  // qsub1
        }
    };

    // V frag loader: d-quarter dq, chunk of iteration jt
    auto vload = [&](int jt, short8* vf) {
        const unsigned short* vch = vb + (size_t)((rbase >> 5) + jt) * (D_ * 32)
                                  + (size_t)(dq * 64 + col) * 32 + g * 8;
#pragma unroll
        for (int dt = 0; dt < 4; ++dt)
            vf[dt] = *(const short8*)(vch + dt * (16 * 32));
    };

    // prologue: P(0) by dq==0 owners; V(0) prefetch by everyone
    short8 vcur[4], vnxt[4];
    vload(0, vcur);
    if (dq == 0) produce(0);
    __syncthreads();

    for (int it = 0; it < 64; ++it) {
        // owner computes next iteration's P (overlaps everyone's PV below)
        if (it < 63 && dq == ((it + 1) & 3)) produce(it + 1);

        // prefetch V for next iteration
        if (it < 63) vload(it + 1, vnxt);

        // PV(it) from P buf it&1
        const unsigned short* pb = pw + (it & 1) * (32 * 40);
        short8 pf0 = *(const short8*)(pb + col * 40 + g * 8);
        short8 pf1 = *(const short8*)(pb + (16 + col) * 40 + g * 8);
#pragma unroll
        for (int dt = 0; dt < 4; ++dt) {
            acc[0][dt] = __builtin_amdgcn_mfma_f32_16x16x32_bf16(vcur[dt], pf0, acc[0][dt], 0, 0, 0);
            acc[1][dt] = __builtin_amdgcn_mfma_f32_16x16x32_bf16(vcur[dt], pf1, acc[1][dt], 0, 0, 0);
        }
        __syncthreads();
#pragma unroll
        for (int dt = 0; dt < 4; ++dt) vcur[dt] = vnxt[dt];
    }

    // combine partials (plain sums: no-max softmax)
#pragma unroll
    for (int qs = 0; qs < 2; ++qs)
#pragma unroll
        for (int dt = 0; dt < 4; ++dt)
#pragma unroll
            for (int r = 0; r < 4; ++r) {
                int d = dq * 64 + dt * 16 + g * 4 + r;
                atomicAdd(&accs[d * 33 + qs * 16 + col], acc[qs][dt][r]);
            }
    if (lane < 16) {
        atomicAdd(&lsum[col], l_run0);
        atomicAdd(&lsum[16 + col], l_run1);
    }
    __syncthreads();

    // epilogue: 512 threads cover 32q x 256d; thread -> (q, 16-d block)
    int qi = tid >> 4;             // 0..31
    int d0 = (tid & 15) * 16;
    int n = q0 + qi;
    int s = n & (S_ - 1), kk = n >> 6;
    const float* xrow = x + (((size_t)(b * S_ + s)) * K_ + kk) * D_;
    float* orow = out + (((size_t)(b * S_ + s)) * K_ + kk) * D_;
    float inv_l = 1.0f / lsum[qi];
    float gam = gamma_p[0];
#pragma unroll
    for (int k = 0; k < 16; k += 4) {
        f32x4 xv = *(const f32x4*)(xrow + d0 + k);
        f32x4 ov;
#pragma unroll
        for (int e = 0; e < 4; ++e)
            ov[e] = gam * accs[(d0 + k + e) * 33 + qi] * inv_l + xv[e];
        *(f32x4*)(orow + d0 + k) = ov;
    }
}

extern "C" void kernel_launch(void* const* d_in, const int* in_sizes, int n_in,
                              void* d_out, int out_size, void* d_ws, size_t ws_size,
                              hipStream_t stream) {
    const float* x  = (const float*)d_in[0];
    const float* Wq = (const float*)d_in[1];
    const float* bq = (const float*)d_in[2];
    const float* Wk = (const float*)d_in[3];
    const float* bk = (const float*)d_in[4];
    const float* Wv = (const float*)d_in[5];
    const float* bv = (const float*)d_in[6];
    const float* gm = (const float*)d_in[7];

    unsigned short* Qh = (unsigned short*)d_ws;                 // [B][N][C] 512KB
    unsigned short* Ql = Qh + (size_t)B_ * N_ * C_;
    unsigned short* Kh = Ql + (size_t)B_ * N_ * C_;
    unsigned short* Kl = Kh + (size_t)B_ * N_ * C_;
    unsigned short* Vm = Kl + (size_t)B_ * N_ * C_;   // [B][N/32][D][32] 4MB
    float* o = (float*)d_out;

    qkv_kernel<<<2560, 256, 0, stream>>>(x, Wq, bq, Wk, bk, Wv, bv,
                                         Qh, Ql, Kh, Kl, Vm);
    attn_kernel<<<256, 512, 0, stream>>>(Qh, Ql, Kh, Kl, Vm, x, gm, o);
}

// Round 9
// 135.365 us; speedup vs baseline: 3.0542x; 1.1570x over previous
//
#include <hip/hip_runtime.h>
#include <stdint.h>
#include <math.h>

using short8   = __attribute__((ext_vector_type(8))) short;
using ushort4v = __attribute__((ext_vector_type(4))) unsigned short;
using f32x4    = __attribute__((ext_vector_type(4))) float;

#define B_ 2
#define S_ 64
#define K_ 64
#define D_ 256
#define C_ 32
#define N_ 4096  /* S_*K_ */

__device__ __forceinline__ float b2f(unsigned short u) {
    unsigned int v = ((unsigned int)u) << 16;
    return __builtin_bit_cast(float, v);
}
__device__ __forceinline__ unsigned short f2b(float f) {   // RNE f32->bf16
    unsigned int x = __builtin_bit_cast(unsigned int, f);
    x += 0x7fffu + ((x >> 16) & 1u);
    return (unsigned short)(x >> 16);
}

// load 8 consecutive f32, produce hi/lo split-bf16 fragments (hi+lo ~ 2^-17 rel)
__device__ __forceinline__ void cvt8(const float* p, short8& hi, short8& lo) {
    f32x4 a = *(const f32x4*)p;
    f32x4 c = *(const f32x4*)(p + 4);
#pragma unroll
    for (int e = 0; e < 4; ++e) {
        unsigned short h0 = f2b(a[e]);
        hi[e]     = (short)h0; lo[e]     = (short)f2b(a[e] - b2f(h0));
        unsigned short h1 = f2b(c[e]);
        hi[e + 4] = (short)h1; lo[e + 4] = (short)f2b(c[e] - b2f(h1));
    }
}
__device__ __forceinline__ void cvt8h(const float* p, short8& hi) {
    f32x4 a = *(const f32x4*)p;
    f32x4 c = *(const f32x4*)(p + 4);
#pragma unroll
    for (int e = 0; e < 4; ++e) {
        hi[e]     = (short)f2b(a[e]);
        hi[e + 4] = (short)f2b(c[e]);
    }
}

// ---------------------------------------------------------------------------
// Kernel 1: QKV projections from f32 x, W. One wave = 16-token x 16-channel.
// ct 0-1 -> Q (hi/lo split), 2-3 -> K (hi/lo), 4-19 -> V (single bf16).
// Q,K stored [B][N][C] bf16 (hi/lo planes). V stored chunk-interleaved
// [B][N/32][D][32] bf16 (one 16 KB contiguous block per 32-key chunk).
// ---------------------------------------------------------------------------
__global__ __launch_bounds__(256) void qkv_kernel(
    const float* __restrict__ x,
    const float* __restrict__ Wq, const float* __restrict__ bq,
    const float* __restrict__ Wk, const float* __restrict__ bk,
    const float* __restrict__ Wv, const float* __restrict__ bv,
    unsigned short* __restrict__ Qh, unsigned short* __restrict__ Ql,
    unsigned short* __restrict__ Kh, unsigned short* __restrict__ Kl,
    unsigned short* __restrict__ Vm)
{
    int widx = blockIdx.x * 4 + (threadIdx.x >> 6);   // 0..10239
    int lane = threadIdx.x & 63;
    int ttile = widx / 20;        // token tile of 16 (0..511)
    int ct    = widx % 20;        // channel tile
    int b  = ttile >> 8;
    int n0 = (ttile & 255) << 4;
    int col = lane & 15, g = lane >> 4;

    int n = n0 + col;
    int s = n & (S_ - 1), kk = n >> 6;
    const float* xrow = x + (((size_t)(b * S_ + s)) * K_ + kk) * D_;

    f32x4 acc = {0.f, 0.f, 0.f, 0.f};

    if (ct < 4) {                       // Q or K: hi/lo split path
        const float* W; const float* bias; int c0;
        if (ct < 2) { W = Wq; bias = bq; c0 = ct * 16; }
        else        { W = Wk; bias = bk; c0 = (ct - 2) * 16; }
        const float* wrow = W + (size_t)(c0 + col) * D_;
#pragma unroll
        for (int dc = 0; dc < 8; ++dc) {
            short8 xh, xl, wh, wl;
            cvt8(xrow + dc * 32 + g * 8, xh, xl);
            cvt8(wrow + dc * 32 + g * 8, wh, wl);
            acc = __builtin_amdgcn_mfma_f32_16x16x32_bf16(xl, wh, acc, 0, 0, 0);
            acc = __builtin_amdgcn_mfma_f32_16x16x32_bf16(xh, wl, acc, 0, 0, 0);
            acc = __builtin_amdgcn_mfma_f32_16x16x32_bf16(xh, wh, acc, 0, 0, 0);
        }
        float bb = bias[c0 + col];
        unsigned short* Th = (ct < 2) ? Qh : Kh;
        unsigned short* Tl = (ct < 2) ? Ql : Kl;
#pragma unroll
        for (int r = 0; r < 4; ++r) {
            int tok = n0 + g * 4 + r;
            float v = acc[r] + bb;
            unsigned short h = f2b(v);
            size_t idx = ((size_t)b * N_ + tok) * C_ + c0 + col;
            Th[idx] = h;
            Tl[idx] = f2b(v - b2f(h));
        }
    } else {                            // V: single-bf16 path
        int c0 = (ct - 4) * 16;
        const float* wrow = Wv + (size_t)(c0 + col) * D_;
#pragma unroll
        for (int dc = 0; dc < 8; ++dc) {
            short8 xh, wh;
            cvt8h(xrow + dc * 32 + g * 8, xh);
            cvt8h(wrow + dc * 32 + g * 8, wh);
            acc = __builtin_amdgcn_mfma_f32_16x16x32_bf16(xh, wh, acc, 0, 0, 0);
        }
        float bb = bv[c0 + col];
        ushort4v st;
#pragma unroll
        for (int r = 0; r < 4; ++r) st[r] = f2b(acc[r] + bb);
        int tok0 = n0 + g * 4;
        size_t vaddr = (((size_t)b * (N_ / 32) + (tok0 >> 5)) * D_ + c0 + col) * 32
                     + (tok0 & 31);
        *(ushort4v*)(Vm + vaddr) = st;
    }
}

// ---------------------------------------------------------------------------
// Kernel 2: flash attention, barrier-free independent waves.
// 256 blocks (1/CU) x 8 waves = d-half(2) x kv-split(4). Block owns 32
// queries; wave (dh,ks) handles keys [ks*1024,(ks+1)*1024) x d-half dh.
// Each wave does its OWN QK^T (duplicated across the dh twins - cheap),
// softmax, P via wave-PRIVATE LDS (in-order DS + lgkmcnt, NO __syncthreads
// in the loop), PV. K and V register-prefetched one iteration ahead
// (fits the 256-reg cap from __launch_bounds__(512,2) - no spill).
// No-max softmax (scores bounded ~34) => combine is plain addition; only
// dh==0 twins contribute the softmax denominator (avoid double count).
// ---------------------------------------------------------------------------
__global__ __launch_bounds__(512, 2) void attn_kernel(
    const unsigned short* __restrict__ Qh, const unsigned short* __restrict__ Ql,
    const unsigned short* __restrict__ Kh, const unsigned short* __restrict__ Kl,
    const unsigned short* __restrict__ Vm, const float* __restrict__ x,
    const float* __restrict__ gamma_p, float* __restrict__ out)
{
    __shared__ unsigned short plds[8][32 * 40];  // per-wave private P, 20 KB
    __shared__ float accs[D_ * 33];              // [d][q] stride 33, 33.8 KB
    __shared__ float lsum[32];

    int tid  = threadIdx.x;
    int wave = tid >> 6;
    int lane = tid & 63;
    int col = lane & 15, g = lane >> 4;
    int dh = wave & 1;            // d-half 0..1
    int ks = wave >> 1;           // kv-split 0..3
    int dbase = dh * 128;
    int jbase = ks * (N_ / 4);

    int bid = blockIdx.x;                   // 256 % 8 == 0 -> bijective swizzle
    int swz = (bid & 7) * 32 + (bid >> 3);
    int b    = swz >> 7;
    int q0   = (swz & 127) << 5;            // 32 queries per block

    for (int i = tid; i < D_ * 33; i += 512) accs[i] = 0.f;
    if (tid < 32) lsum[tid] = 0.f;
    __syncthreads();

    // Q fragments for both q-subtiles (hi/lo planes)
    size_t qoff0 = ((size_t)b * N_ + q0 + col) * C_ + g * 8;
    size_t qoff1 = ((size_t)b * N_ + q0 + 16 + col) * C_ + g * 8;
    short8 qfh0 = *(const short8*)(Qh + qoff0);
    short8 qfl0 = *(const short8*)(Ql + qoff0);
    short8 qfh1 = *(const short8*)(Qh + qoff1);
    short8 qfl1 = *(const short8*)(Ql + qoff1);

    f32x4 acc[2][8];
#pragma unroll
    for (int qs = 0; qs < 2; ++qs)
#pragma unroll
        for (int dt = 0; dt < 8; ++dt) acc[qs][dt] = (f32x4){0.f, 0.f, 0.f, 0.f};
    float l_run0 = 0.f, l_run1 = 0.f;

    const unsigned short* kbh = Kh + (size_t)b * N_ * C_;
    const unsigned short* kbl = Kl + (size_t)b * N_ * C_;
    const unsigned short* vb  = Vm + (size_t)b * N_ * D_;   // [N/32][D][32]
    unsigned short* pb = plds[wave];

    // ---- prefetch helpers (addresses only depend on it) ----
    auto kaddr0 = [&](int it) { return (size_t)(jbase + it * 32 + col) * C_ + g * 8; };
    auto kaddr1 = [&](int it) { return (size_t)(jbase + it * 32 + 16 + col) * C_ + g * 8; };
    auto vaddr  = [&](int it) {
        return (size_t)((jbase >> 5) + it) * (D_ * 32) + (size_t)(dbase + col) * 32 + g * 8;
    };

    // prologue: load K(0), V(0)
    short8 kh0 = *(const short8*)(kbh + kaddr0(0));
    short8 kl0 = *(const short8*)(kbl + kaddr0(0));
    short8 kh1 = *(const short8*)(kbh + kaddr1(0));
    short8 kl1 = *(const short8*)(kbl + kaddr1(0));
    short8 vcur[8];
    {
        const unsigned short* vp = vb + vaddr(0);
#pragma unroll
        for (int dt = 0; dt < 8; ++dt)
            vcur[dt] = *(const short8*)(vp + dt * (16 * 32));
    }

    for (int it = 0; it < 32; ++it) {
        // issue next iteration's K and V loads first (hide under compute)
        short8 nkh0, nkl0, nkh1, nkl1, vnxt[8];
        int itn = (it + 1 < 32) ? it + 1 : 0;
        nkh0 = *(const short8*)(kbh + kaddr0(itn));
        nkl0 = *(const short8*)(kbl + kaddr0(itn));
        nkh1 = *(const short8*)(kbh + kaddr1(itn));
        nkl1 = *(const short8*)(kbl + kaddr1(itn));
        {
            const unsigned short* vp = vb + vaddr(itn);
#pragma unroll
            for (int dt = 0; dt < 8; ++dt)
                vnxt[dt] = *(const short8*)(vp + dt * (16 * 32));
        }

        // QK^T (split-bf16 3-chain) on current K: D[key][q]
        f32x4 z = {0.f, 0.f, 0.f, 0.f};
        f32x4 s00 = __builtin_amdgcn_mfma_f32_16x16x32_bf16(kl0, qfh0, z, 0, 0, 0);
        s00 = __builtin_amdgcn_mfma_f32_16x16x32_bf16(kh0, qfl0, s00, 0, 0, 0);
        s00 = __builtin_amdgcn_mfma_f32_16x16x32_bf16(kh0, qfh0, s00, 0, 0, 0);
        f32x4 s01 = __builtin_amdgcn_mfma_f32_16x16x32_bf16(kl1, qfh0, z, 0, 0, 0);
        s01 = __builtin_amdgcn_mfma_f32_16x16x32_bf16(kh1, qfl0, s01, 0, 0, 0);
        s01 = __builtin_amdgcn_mfma_f32_16x16x32_bf16(kh1, qfh0, s01, 0, 0, 0);
        f32x4 s10 = __builtin_amdgcn_mfma_f32_16x16x32_bf16(kl0, qfh1, z, 0, 0, 0);
        s10 = __builtin_amdgcn_mfma_f32_16x16x32_bf16(kh0, qfl1, s10, 0, 0, 0);
        s10 = __builtin_amdgcn_mfma_f32_16x16x32_bf16(kh0, qfh1, s10, 0, 0, 0);
        f32x4 s11 = __builtin_amdgcn_mfma_f32_16x16x32_bf16(kl1, qfh1, z, 0, 0, 0);
        s11 = __builtin_amdgcn_mfma_f32_16x16x32_bf16(kh1, qfl1, s11, 0, 0, 0);
        s11 = __builtin_amdgcn_mfma_f32_16x16x32_bf16(kh1, qfh1, s11, 0, 0, 0);

        // softmax numerators (no-max: scores bounded ~34; clamp is safety)
        float pa[4], pc[4], pe[4], pg[4], sl0 = 0.f, sl1 = 0.f;
#pragma unroll
        for (int r = 0; r < 4; ++r) { pa[r] = __expf(fminf(s00[r], 60.f)); sl0 += pa[r]; }
#pragma unroll
        for (int r = 0; r < 4; ++r) { pc[r] = __expf(fminf(s01[r], 60.f)); sl0 += pc[r]; }
#pragma unroll
        for (int r = 0; r < 4; ++r) { pe[r] = __expf(fminf(s10[r], 60.f)); sl1 += pe[r]; }
#pragma unroll
        for (int r = 0; r < 4; ++r) { pg[r] = __expf(fminf(s11[r], 60.f)); sl1 += pg[r]; }
        sl0 += __shfl_xor(sl0, 16); sl0 += __shfl_xor(sl0, 32);
        sl1 += __shfl_xor(sl1, 16); sl1 += __shfl_xor(sl1, 32);
        l_run0 += sl0; l_run1 += sl1;

        // stage P[q][j] (wave-private LDS, padded stride 40)
        ushort4v wa, wc, we, wg;
#pragma unroll
        for (int r = 0; r < 4; ++r) {
            wa[r] = f2b(pa[r]); wc[r] = f2b(pc[r]);
            we[r] = f2b(pe[r]); wg[r] = f2b(pg[r]);
        }
        *(ushort4v*)(pb + col * 40 + g * 4)             = wa;  // qsub0, keys 0..15
        *(ushort4v*)(pb + col * 40 + 16 + g * 4)        = wc;  // qsub0, keys 16..31
        *(ushort4v*)(pb + (16 + col) * 40 + g * 4)      = we;  // qsub1
        *(ushort4v*)(pb + (16 + col) * 40 + 16 + g * 4) = wg;
        asm volatile("s_waitcnt lgkmcnt(0)" ::: "memory");
        __builtin_amdgcn_sched_barrier(0);

        short8 pf0 = *(const short8*)(pb + col * 40 + g * 8);
        short8 pf1 = *(const short8*)(pb + (16 + col) * 40 + g * 8);
        asm volatile("" ::: "memory");

        // PV on own d-half
#pragma unroll
        for (int dt = 0; dt < 8; ++dt) {
            acc[0][dt] = __builtin_amdgcn_mfma_f32_16x16x32_bf16(vcur[dt], pf0, acc[0][dt], 0, 0, 0);
            acc[1][dt] = __builtin_amdgcn_mfma_f32_16x16x32_bf16(vcur[dt], pf1, acc[1][dt], 0, 0, 0);
        }

        kh0 = nkh0; kl0 = nkl0; kh1 = nkh1; kl1 = nkl1;
#pragma unroll
        for (int dt = 0; dt < 8; ++dt) vcur[dt] = vnxt[dt];
    }

    // combine partials (plain sums: no-max softmax)
#pragma unroll
    for (int qs = 0; qs < 2; ++qs)
#pragma unroll
        for (int dt = 0; dt < 8; ++dt)
#pragma unroll
            for (int r = 0; r < 4; ++r) {
                int d = dbase + dt * 16 + g * 4 + r;
                atomicAdd(&accs[d * 33 + qs * 16 + col], acc[qs][dt][r]);
            }
    if (dh == 0 && lane < 16) {          // one twin per key-range counts l
        atomicAdd(&lsum[col], l_run0);
        atomicAdd(&lsum[16 + col], l_run1);
    }
    __syncthreads();

    // epilogue: 512 threads cover 32q x 256d; thread -> (q, 16-d block)
    int qi = tid >> 4;             // 0..31
    int d0 = (tid & 15) * 16;
    int n = q0 + qi;
    int s = n & (S_ - 1), kk = n >> 6;
    const float* xrow = x + (((size_t)(b * S_ + s)) * K_ + kk) * D_;
    float* orow = out + (((size_t)(b * S_ + s)) * K_ + kk) * D_;
    float inv_l = 1.0f / lsum[qi];
    float gam = gamma_p[0];
#pragma unroll
    for (int k = 0; k < 16; k += 4) {
        f32x4 xv = *(const f32x4*)(xrow + d0 + k);
        f32x4 ov;
#pragma unroll
        for (int e = 0; e < 4; ++e)
            ov[e] = gam * accs[(d0 + k + e) * 33 + qi] * inv_l + xv[e];
        *(f32x4*)(orow + d0 + k) = ov;
    }
}

extern "C" void kernel_launch(void* const* d_in, const int* in_sizes, int n_in,
                              void* d_out, int out_size, void* d_ws, size_t ws_size,
                              hipStream_t stream) {
    const float* x  = (const float*)d_in[0];
    const float* Wq = (const float*)d_in[1];
    const float* bq = (const float*)d_in[2];
    const float* Wk = (const float*)d_in[3];
    const float* bk = (const float*)d_in[4];
    const float* Wv = (const float*)d_in[5];
    const float* bv = (const float*)d_in[6];
    const float* gm = (const float*)d_in[7];

    unsigned short* Qh = (unsigned short*)d_ws;                 // [B][N][C] 512KB
    unsigned short* Ql = Qh + (size_t)B_ * N_ * C_;
    unsigned short* Kh = Ql + (size_t)B_ * N_ * C_;
    unsigned short* Kl = Kh + (size_t)B_ * N_ * C_;
    unsigned short* Vm = Kl + (size_t)B_ * N_ * C_;   // [B][N/32][D][32] 4MB
    float* o = (float*)d_out;

    qkv_kernel<<<2560, 256, 0, stream>>>(x, Wq, bq, Wk, bk, Wv, bv,
                                         Qh, Ql, Kh, Kl, Vm);
    attn_kernel<<<256, 512, 0, stream>>>(Qh, Ql, Kh, Kl, Vm, x, gm, o);
}

// Round 10
// 86.349 us; speedup vs baseline: 4.7880x; 1.5677x over previous
//
#include <hip/hip_runtime.h>
#include <stdint.h>
#include <math.h>

using short8   = __attribute__((ext_vector_type(8))) short;
using ushort4v = __attribute__((ext_vector_type(4))) unsigned short;
using f32x4    = __attribute__((ext_vector_type(4))) float;

#define B_ 2
#define S_ 64
#define K_ 64
#define D_ 256
#define C_ 32
#define N_ 4096  /* S_*K_ */
#define LOG2E 1.4426950408889634f

__device__ __forceinline__ float b2f(unsigned short u) {
    unsigned int v = ((unsigned int)u) << 16;
    return __builtin_bit_cast(float, v);
}
__device__ __forceinline__ unsigned short f2b(float f) {   // RNE f32->bf16
    unsigned int x = __builtin_bit_cast(unsigned int, f);
    x += 0x7fffu + ((x >> 16) & 1u);
    return (unsigned short)(x >> 16);
}

// ---------------------------------------------------------------------------
// Kernel 0: W/bias pre-convert. Concatenated out-channels: 0-31 Q (x log2e),
// 32-63 K, 64-319 V. Wh/Wl bf16 hi/lo planes [320][256]; bcat f32[320].
// ---------------------------------------------------------------------------
__global__ __launch_bounds__(256) void wcvt_kernel(
    const float* __restrict__ Wq, const float* __restrict__ bq,
    const float* __restrict__ Wk, const float* __restrict__ bk,
    const float* __restrict__ Wv, const float* __restrict__ bv,
    unsigned short* __restrict__ Wh, unsigned short* __restrict__ Wl,
    float* __restrict__ bcat)
{
    int oc = blockIdx.x;            // 0..319
    int d  = threadIdx.x;           // 0..255
    float w;
    if (oc < 32)       w = Wq[oc * 256 + d] * LOG2E;
    else if (oc < 64)  w = Wk[(oc - 32) * 256 + d];
    else               w = Wv[(oc - 64) * 256 + d];
    unsigned short h = f2b(w);
    Wh[oc * 256 + d] = h;
    Wl[oc * 256 + d] = f2b(w - b2f(h));
    if (d == 0) {
        float bb;
        if (oc < 32)      bb = bq[oc] * LOG2E;
        else if (oc < 64) bb = bk[oc - 32];
        else              bb = bv[oc - 64];
        bcat[oc] = bb;
    }
}

// ---------------------------------------------------------------------------
// Kernel 1: QKV projections. 512 blocks (one 16-token tile each) x 4 waves.
// x tile staged ONCE in LDS as hi/lo bf16 planes (XOR-swizzled granules) ->
// x HBM/L2 traffic /20 vs reading per channel-tile. W read from pre-converted
// bf16 planes (no cvt in loop). Wave w handles ct {w, w+4, .., w+16}
// (20 channel-tiles of 16: Q 0-1 hi/lo-split out, K 2-3, V 4-19) - balanced
// 56 MFMA per wave. Q,K stored [B][N][C] hi/lo; V chunk-interleaved
// [B][N/32][D][32].
// ---------------------------------------------------------------------------
__global__ __launch_bounds__(256) void qkv_kernel(
    const float* __restrict__ x,
    const unsigned short* __restrict__ Wh, const unsigned short* __restrict__ Wl,
    const float* __restrict__ bcat,
    unsigned short* __restrict__ Qh, unsigned short* __restrict__ Ql,
    unsigned short* __restrict__ Kh, unsigned short* __restrict__ Kl,
    unsigned short* __restrict__ Vm)
{
    __shared__ unsigned short lxh[16 * 256];   // [tok][d] bf16-hi, swizzled
    __shared__ unsigned short lxl[16 * 256];   // bf16-lo

    int tid = threadIdx.x;
    int bid = blockIdx.x;
    int b  = bid >> 8;
    int n0 = (bid & 255) << 4;

    // ---- stage x tile: thread -> (token tt, 16-d group dg0) ----
    {
        int tt = tid >> 4, dg0 = (tid & 15) * 16;
        int n = n0 + tt;
        int s = n & 63, kk = n >> 6;
        const float* xr = x + (((size_t)(b * S_ + s)) * K_ + kk) * D_ + dg0;
        short8 h0, l0, h1, l1;
#pragma unroll
        for (int e = 0; e < 8; ++e) {
            float v = xr[e];
            unsigned short hh = f2b(v);
            h0[e] = (short)hh; l0[e] = (short)f2b(v - b2f(hh));
        }
#pragma unroll
        for (int e = 0; e < 8; ++e) {
            float v = xr[8 + e];
            unsigned short hh = f2b(v);
            h1[e] = (short)hh; l1[e] = (short)f2b(v - b2f(hh));
        }
        int m0 = dg0 >> 3;                       // 16B-granule index (even)
        int sw0 = ((m0 ^ (tt & 7)) << 3);
        int sw1 = (((m0 + 1) ^ (tt & 7)) << 3);
        *(short8*)(lxh + tt * 256 + sw0) = h0;
        *(short8*)(lxh + tt * 256 + sw1) = h1;
        *(short8*)(lxl + tt * 256 + sw0) = l0;
        *(short8*)(lxl + tt * 256 + sw1) = l1;
    }
    __syncthreads();

    int wave = tid >> 6, lane = tid & 63;
    int col = lane & 15, g = lane >> 4;

#pragma unroll
    for (int i = 0; i < 5; ++i) {
        int ct = wave + i * 4;                   // 0..19
        int oc0 = ct * 16;
        const unsigned short* whr = Wh + (size_t)(oc0 + col) * 256;
        const unsigned short* wlr = Wl + (size_t)(oc0 + col) * 256;
        f32x4 acc = {0.f, 0.f, 0.f, 0.f};

        if (ct < 4) {                            // Q/K: split-bf16 3-chain
#pragma unroll
            for (int dc = 0; dc < 8; ++dc) {
                int sw = (((dc * 4 + g) ^ (col & 7)) << 3);
                short8 xh8 = *(const short8*)(lxh + col * 256 + sw);
                short8 xl8 = *(const short8*)(lxl + col * 256 + sw);
                short8 wh8 = *(const short8*)(whr + dc * 32 + g * 8);
                short8 wl8 = *(const short8*)(wlr + dc * 32 + g * 8);
                acc = __builtin_amdgcn_mfma_f32_16x16x32_bf16(xl8, wh8, acc, 0, 0, 0);
                acc = __builtin_amdgcn_mfma_f32_16x16x32_bf16(xh8, wl8, acc, 0, 0, 0);
                acc = __builtin_amdgcn_mfma_f32_16x16x32_bf16(xh8, wh8, acc, 0, 0, 0);
            }
            float bb = bcat[oc0 + col];
            unsigned short* Th = (ct < 2) ? Qh : Kh;
            unsigned short* Tl = (ct < 2) ? Ql : Kl;
            int c0 = (ct & 1) * 16;
#pragma unroll
            for (int r = 0; r < 4; ++r) {
                int tok = n0 + g * 4 + r;
                float v = acc[r] + bb;
                unsigned short hh = f2b(v);
                size_t idx = ((size_t)b * N_ + tok) * C_ + c0 + col;
                Th[idx] = hh;
                Tl[idx] = f2b(v - b2f(hh));
            }
        } else {                                 // V: single bf16
#pragma unroll
            for (int dc = 0; dc < 8; ++dc) {
                int sw = (((dc * 4 + g) ^ (col & 7)) << 3);
                short8 xh8 = *(const short8*)(lxh + col * 256 + sw);
                short8 wh8 = *(const short8*)(whr + dc * 32 + g * 8);
                acc = __builtin_amdgcn_mfma_f32_16x16x32_bf16(xh8, wh8, acc, 0, 0, 0);
            }
            float bb = bcat[oc0 + col];
            int c0 = oc0 - 64;
            ushort4v st;
#pragma unroll
            for (int r = 0; r < 4; ++r) st[r] = f2b(acc[r] + bb);
            int tok0 = n0 + g * 4;
            size_t vaddr = (((size_t)b * (N_ / 32) + (tok0 >> 5)) * D_ + c0 + col) * 32
                         + (tok0 & 31);
            *(ushort4v*)(Vm + vaddr) = st;
        }
    }
}

// ---------------------------------------------------------------------------
// Kernel 2: flash attention, 128-q tiles x key-split-4, barrier-free.
// 256 blocks: bid&7 = (b*4 + ks) -> one (batch, key-quarter) per XCD (L2-
// resident ~1.2MB); qt = bid>>3. 8 waves = 4 q-quarters x 2 d-halves; each
// wave: 32q x 128d over 1024 keys in 32-key iters (QK duplicated across the
// dh twins - cheap). K read identically by all 8 waves, V-half by 4 -> L1
// broadcast. P via wave-private LDS. Raw partials dumped coalesced to
// O_part (+ lsum_part); epilogue kernel combines. exp2-domain softmax
// (Q pre-scaled by log2e), no-max (|s| < ~50 < 80 clamp).
// ---------------------------------------------------------------------------
__global__ __launch_bounds__(512, 2) void attn_kernel(
    const unsigned short* __restrict__ Qh, const unsigned short* __restrict__ Ql,
    const unsigned short* __restrict__ Kh, const unsigned short* __restrict__ Kl,
    const unsigned short* __restrict__ Vm,
    float* __restrict__ O_part, float* __restrict__ lsum_part)
{
    __shared__ unsigned short plds[8][32 * 40];  // per-wave private P

    int tid  = threadIdx.x;
    int wave = tid >> 6;
    int lane = tid & 63;
    int col = lane & 15, g = lane >> 4;
    int qq = wave >> 1;           // q-quarter 0..3
    int dh = wave & 1;            // d-half 0..1
    int dbase = dh * 128;

    int bid = blockIdx.x;
    int x7 = bid & 7;
    int b  = x7 >> 2;
    int ks = x7 & 3;
    int qt = bid >> 3;            // 0..31 (q-tile within batch)
    int q0 = qt * 128 + qq * 32;  // this wave's 32 queries (within batch)
    int jbase = ks * (N_ / 4);

    // Q fragments for both 16-q subtiles (hi/lo planes)
    size_t qoff0 = ((size_t)b * N_ + q0 + col) * C_ + g * 8;
    size_t qoff1 = ((size_t)b * N_ + q0 + 16 + col) * C_ + g * 8;
    short8 qfh0 = *(const short8*)(Qh + qoff0);
    short8 qfl0 = *(const short8*)(Ql + qoff0);
    short8 qfh1 = *(const short8*)(Qh + qoff1);
    short8 qfl1 = *(const short8*)(Ql + qoff1);

    f32x4 acc[2][8];
#pragma unroll
    for (int qs = 0; qs < 2; ++qs)
#pragma unroll
        for (int dt = 0; dt < 8; ++dt) acc[qs][dt] = (f32x4){0.f, 0.f, 0.f, 0.f};
    float l_run0 = 0.f, l_run1 = 0.f;

    const unsigned short* kbh = Kh + (size_t)b * N_ * C_;
    const unsigned short* kbl = Kl + (size_t)b * N_ * C_;
    const unsigned short* vb  = Vm + (size_t)b * N_ * D_;   // [N/32][D][32]
    unsigned short* pb = plds[wave];

    auto kaddr0 = [&](int it) { return (size_t)(jbase + it * 32 + col) * C_ + g * 8; };
    auto kaddr1 = [&](int it) { return (size_t)(jbase + it * 32 + 16 + col) * C_ + g * 8; };
    auto vaddr  = [&](int it) {
        return (size_t)(ks * 32 + it) * (D_ * 32) + (size_t)(dbase + col) * 32 + g * 8;
    };

    // prologue: K(0), V(0)
    short8 kh0 = *(const short8*)(kbh + kaddr0(0));
    short8 kl0 = *(const short8*)(kbl + kaddr0(0));
    short8 kh1 = *(const short8*)(kbh + kaddr1(0));
    short8 kl1 = *(const short8*)(kbl + kaddr1(0));
    short8 vcur[8];
    {
        const unsigned short* vp = vb + vaddr(0);
#pragma unroll
        for (int dt = 0; dt < 8; ++dt)
            vcur[dt] = *(const short8*)(vp + dt * (16 * 32));
    }

    for (int it = 0; it < 32; ++it) {
        // issue next iteration's K and V loads first
        short8 nkh0, nkl0, nkh1, nkl1, vnxt[8];
        int itn = (it + 1 < 32) ? it + 1 : 0;
        nkh0 = *(const short8*)(kbh + kaddr0(itn));
        nkl0 = *(const short8*)(kbl + kaddr0(itn));
        nkh1 = *(const short8*)(kbh + kaddr1(itn));
        nkl1 = *(const short8*)(kbl + kaddr1(itn));
        {
            const unsigned short* vp = vb + vaddr(itn);
#pragma unroll
            for (int dt = 0; dt < 8; ++dt)
                vnxt[dt] = *(const short8*)(vp + dt * (16 * 32));
        }

        // QK^T (split-bf16 3-chain): D[key][q], exp2-domain scores
        f32x4 z = {0.f, 0.f, 0.f, 0.f};
        f32x4 s00 = __builtin_amdgcn_mfma_f32_16x16x32_bf16(kl0, qfh0, z, 0, 0, 0);
        s00 = __builtin_amdgcn_mfma_f32_16x16x32_bf16(kh0, qfl0, s00, 0, 0, 0);
        s00 = __builtin_amdgcn_mfma_f32_16x16x32_bf16(kh0, qfh0, s00, 0, 0, 0);
        f32x4 s01 = __builtin_amdgcn_mfma_f32_16x16x32_bf16(kl1, qfh0, z, 0, 0, 0);
        s01 = __builtin_amdgcn_mfma_f32_16x16x32_bf16(kh1, qfl0, s01, 0, 0, 0);
        s01 = __builtin_amdgcn_mfma_f32_16x16x32_bf16(kh1, qfh0, s01, 0, 0, 0);
        f32x4 s10 = __builtin_amdgcn_mfma_f32_16x16x32_bf16(kl0, qfh1, z, 0, 0, 0);
        s10 = __builtin_amdgcn_mfma_f32_16x16x32_bf16(kh0, qfl1, s10, 0, 0, 0);
        s10 = __builtin_amdgcn_mfma_f32_16x16x32_bf16(kh0, qfh1, s10, 0, 0, 0);
        f32x4 s11 = __builtin_amdgcn_mfma_f32_16x16x32_bf16(kl1, qfh1, z, 0, 0, 0);
        s11 = __builtin_amdgcn_mfma_f32_16x16x32_bf16(kh1, qfl1, s11, 0, 0, 0);
        s11 = __builtin_amdgcn_mfma_f32_16x16x32_bf16(kh1, qfh1, s11, 0, 0, 0);

        // p = exp2(s'); |s'| <~50, clamp 80 is pure safety
        float pa[4], pc[4], pe[4], pg[4], sl0 = 0.f, sl1 = 0.f;
#pragma unroll
        for (int r = 0; r < 4; ++r) { pa[r] = exp2f(fminf(s00[r], 80.f)); sl0 += pa[r]; }
#pragma unroll
        for (int r = 0; r < 4; ++r) { pc[r] = exp2f(fminf(s01[r], 80.f)); sl0 += pc[r]; }
#pragma unroll
        for (int r = 0; r < 4; ++r) { pe[r] = exp2f(fminf(s10[r], 80.f)); sl1 += pe[r]; }
#pragma unroll
        for (int r = 0; r < 4; ++r) { pg[r] = exp2f(fminf(s11[r], 80.f)); sl1 += pg[r]; }
        sl0 += __shfl_xor(sl0, 16); sl0 += __shfl_xor(sl0, 32);
        sl1 += __shfl_xor(sl1, 16); sl1 += __shfl_xor(sl1, 32);
        l_run0 += sl0; l_run1 += sl1;

        // stage P[q][j] (wave-private LDS, padded stride 40)
        ushort4v wa, wc, we, wg;
#pragma unroll
        for (int r = 0; r < 4; ++r) {
            wa[r] = f2b(pa[r]); wc[r] = f2b(pc[r]);
            we[r] = f2b(pe[r]); wg[r] = f2b(pg[r]);
        }
        *(ushort4v*)(pb + col * 40 + g * 4)             = wa;
        *(ushort4v*)(pb + col * 40 + 16 + g * 4)        = wc;
        *(ushort4v*)(pb + (16 + col) * 40 + g * 4)      = we;
        *(ushort4v*)(pb + (16 + col) * 40 + 16 + g * 4) = wg;
        asm volatile("s_waitcnt lgkmcnt(0)" ::: "memory");
        __builtin_amdgcn_sched_barrier(0);

        short8 pf0 = *(const short8*)(pb + col * 40 + g * 8);
        short8 pf1 = *(const short8*)(pb + (16 + col) * 40 + g * 8);
        asm volatile("" ::: "memory");

        // PV on own d-half
#pragma unroll
        for (int dt = 0; dt < 8; ++dt) {
            acc[0][dt] = __builtin_amdgcn_mfma_f32_16x16x32_bf16(vcur[dt], pf0, acc[0][dt], 0, 0, 0);
            acc[1][dt] = __builtin_amdgcn_mfma_f32_16x16x32_bf16(vcur[dt], pf1, acc[1][dt], 0, 0, 0);
        }

        kh0 = nkh0; kl0 = nkl0; kh1 = nkh1; kl1 = nkl1;
#pragma unroll
        for (int dt = 0; dt < 8; ++dt) vcur[dt] = vnxt[dt];
    }

    // dump raw partials, coalesced: per (qs,dt) one 1KB wave-store of a
    // 16q x 16d tile in [q][d] order at f32 offset col*16 + g*4.
    float* op = O_part + (size_t)bid * 32768 + wave * 4096;
#pragma unroll
    for (int qs = 0; qs < 2; ++qs)
#pragma unroll
        for (int dt = 0; dt < 8; ++dt) {
            int j = qs * 8 + dt;
            *(f32x4*)(op + j * 256 + col * 16 + g * 4) = acc[qs][dt];
        }
    if (dh == 0 && g == 0) {
        lsum_part[bid * 128 + qq * 32 + col]      = l_run0;
        lsum_part[bid * 128 + qq * 32 + 16 + col] = l_run1;
    }
}

// ---------------------------------------------------------------------------
// Kernel 3: epilogue. out[b,s,k,d] = gamma * (sum_ks O_part)/(sum_ks l) + x.
// Thread -> one f32x4 of output (fully coalesced out/x; O_part reads are
// 16 full lines per wave).
// ---------------------------------------------------------------------------
__global__ __launch_bounds__(256) void epi_kernel(
    const float* __restrict__ O_part, const float* __restrict__ lsum_part,
    const float* __restrict__ x, const float* __restrict__ gamma_p,
    float* __restrict__ out)
{
    int gid = blockIdx.x * 256 + threadIdx.x;   // 0..524287
    int d  = (gid & 63) * 4;
    int nl = gid >> 6;
    int b  = nl >> 12;
    int n  = nl & (N_ - 1);

    int qt = n >> 7, qq = (n >> 5) & 3, qs = (n >> 4) & 1, col = n & 15;
    int dh = d >> 7, dt = (d >> 4) & 7;
    int w = qq * 2 + dh, j = qs * 8 + dt;
    int boff = w * 4096 + j * 256 + col * 16 + (d & 15);
    int loff = qq * 32 + qs * 16 + col;

    f32x4 acc = {0.f, 0.f, 0.f, 0.f};
    float l = 0.f;
#pragma unroll
    for (int ks = 0; ks < 4; ++ks) {
        int bid = qt * 8 + b * 4 + ks;
        f32x4 p = *(const f32x4*)(O_part + (size_t)bid * 32768 + boff);
        acc[0] += p[0]; acc[1] += p[1]; acc[2] += p[2]; acc[3] += p[3];
        l += lsum_part[bid * 128 + loff];
    }
    float scale = gamma_p[0] / l;
    int s = n & 63, kk = n >> 6;
    size_t o = (((size_t)(b * S_ + s)) * K_ + kk) * D_ + d;
    f32x4 xv = *(const f32x4*)(x + o);
    f32x4 ov;
#pragma unroll
    for (int e = 0; e < 4; ++e) ov[e] = acc[e] * scale + xv[e];
    *(f32x4*)(out + o) = ov;
}

extern "C" void kernel_launch(void* const* d_in, const int* in_sizes, int n_in,
                              void* d_out, int out_size, void* d_ws, size_t ws_size,
                              hipStream_t stream) {
    const float* x  = (const float*)d_in[0];
    const float* Wq = (const float*)d_in[1];
    const float* bq = (const float*)d_in[2];
    const float* Wk = (const float*)d_in[3];
    const float* bk = (const float*)d_in[4];
    const float* Wv = (const float*)d_in[5];
    const float* bv = (const float*)d_in[6];
    const float* gm = (const float*)d_in[7];

    char* ws = (char*)d_ws;
    unsigned short* Wh   = (unsigned short*)(ws);                 // 160KB
    unsigned short* Wl   = (unsigned short*)(ws + 0x40000);       // 160KB
    float*          bcat = (float*)         (ws + 0x80000);       // 1.3KB
    unsigned short* Qh   = (unsigned short*)(ws + 0x100000);      // 512KB
    unsigned short* Ql   = (unsigned short*)(ws + 0x180000);
    unsigned short* Kh   = (unsigned short*)(ws + 0x200000);
    unsigned short* Kl   = (unsigned short*)(ws + 0x280000);
    unsigned short* Vm   = (unsigned short*)(ws + 0x300000);      // 4MB
    float*          Op   = (float*)         (ws + 0x700000);      // 32MB
    float*          lp   = (float*)         (ws + 0x2700000);     // 128KB
    float* o = (float*)d_out;

    wcvt_kernel<<<320, 256, 0, stream>>>(Wq, bq, Wk, bk, Wv, bv, Wh, Wl, bcat);
    qkv_kernel<<<512, 256, 0, stream>>>(x, Wh, Wl, bcat, Qh, Ql, Kh, Kl, Vm);
    attn_kernel<<<256, 512, 0, stream>>>(Qh, Ql, Kh, Kl, Vm, Op, lp);
    epi_kernel<<<2048, 256, 0, stream>>>(Op, lp, x, gm, o);
}